// Round 8
// baseline (393.147 us; speedup 1.0000x reference)
//
#include <hip/hip_runtime.h>
#include <math.h>

// Problem constants (fixed by reference):
// B=2, L=2048, D=2048, H=16, G=4, HD=128, EPS=1e-6, scale = 1/HD^2 = 1/16384
#define SEQ 2048
#define DMODEL 2048
#define NHQ 16
#define NHK 4

typedef __attribute__((ext_vector_type(8))) short short8;
typedef __attribute__((ext_vector_type(4))) float floatx4;

__device__ __forceinline__ unsigned short f2bf(float f) {
  unsigned int u = __builtin_bit_cast(unsigned int, f);
  u += 0x7fffu + ((u >> 16) & 1u);   // round-to-nearest-even
  return (unsigned short)(u >> 16);
}
__device__ __forceinline__ float bf2f(unsigned short s) {
  unsigned int u = ((unsigned int)s) << 16;
  return __builtin_bit_cast(float, u);
}

// ---------------------------------------------------------------------------
// One prep launch: cast x -> bf16 AND all 4 weight transposes.
// grid (64, 64, 4), block (32,8).
//  z=0: Wq -> wqkv_t[0:2048]           z=1: Wo -> wo_t
//  z=2: bx<16 Wk -> wqkv_t[2048:2560]; bx in [16,32) Wv -> wqkv_t[2560:3072]
//  z=3: cast x (block = 2048 contiguous elements)
// ---------------------------------------------------------------------------
__global__ __launch_bounds__(256) void prep(const float* __restrict__ x,
                                            const float* __restrict__ Wq,
                                            const float* __restrict__ Wk,
                                            const float* __restrict__ Wv,
                                            const float* __restrict__ Wo,
                                            unsigned short* __restrict__ x_bf,
                                            unsigned short* __restrict__ wqkv_t,
                                            unsigned short* __restrict__ wo_t) {
  const int z = blockIdx.z;
  const int tx = threadIdx.x, ty = threadIdx.y;
  if (z == 3) {
    const size_t base = ((size_t)(blockIdx.y * 64 + blockIdx.x)) * 2048 + (ty * 32 + tx) * 8;
    const float4 v0 = *(const float4*)(x + base);
    const float4 v1 = *(const float4*)(x + base + 4);
    ushort4 w0, w1;
    w0.x = f2bf(v0.x); w0.y = f2bf(v0.y); w0.z = f2bf(v0.z); w0.w = f2bf(v0.w);
    w1.x = f2bf(v1.x); w1.y = f2bf(v1.y); w1.z = f2bf(v1.z); w1.w = f2bf(v1.w);
    *(ushort4*)(x_bf + base) = w0;
    *(ushort4*)(x_bf + base + 4) = w1;
    return;
  }
  int bx = blockIdx.x;
  const float* in;
  unsigned short* out;
  int C;
  const int R = 2048;
  if (z == 0)      { in = Wq; out = wqkv_t;                          C = 2048; }
  else if (z == 1) { in = Wo; out = wo_t;                            C = 2048; }
  else {
    if (bx < 16)      { in = Wk; out = wqkv_t + (size_t)2048 * 2048; C = 512; }
    else if (bx < 32) { in = Wv; out = wqkv_t + (size_t)2560 * 2048; C = 512; bx -= 16; }
    else return;
  }
  __shared__ float tile[32][33];
  const int c0 = bx * 32, r0 = blockIdx.y * 32;
#pragma unroll
  for (int j = 0; j < 4; ++j)
    tile[ty + j * 8][tx] = in[(size_t)(r0 + ty + j * 8) * C + c0 + tx];
  __syncthreads();
#pragma unroll
  for (int j = 0; j < 4; ++j)
    out[(size_t)(c0 + ty + j * 8) * R + r0 + tx] = f2bf(tile[tx][ty + j * 8]);
}

// ---------------------------------------------------------------------------
// Fused QKV GEMM + RMSNorm + RoPE + V-transpose (unchanged from R7).
// Each 128-col block tile is exactly one head: bx<16 Q, 16..19 K, 20..23 V.
// ---------------------------------------------------------------------------
__global__ __launch_bounds__(256) void gemm_qkv_fused(const unsigned short* __restrict__ A,
                                                      const unsigned short* __restrict__ Bt,
                                                      unsigned short* __restrict__ qout,
                                                      unsigned short* __restrict__ kout,
                                                      unsigned short* __restrict__ vout,
                                                      const float* __restrict__ q_scale,
                                                      const float* __restrict__ k_scale,
                                                      const float* __restrict__ cosb,
                                                      const float* __restrict__ sinb) {
  __shared__ unsigned short smem[128 * 129];   // 33 KB; first 16 KB doubles as As|Bs
  unsigned short* As = smem;
  unsigned short* Bs = smem + 128 * 32;

  const int tid = threadIdx.x;
  const int wave = tid >> 6;
  const int lane = tid & 63;
  const int bm = blockIdx.y * 128;
  const int bx = blockIdx.x;            // head-block 0..23
  const int bn = bx * 128;
  const int wr = wave >> 1;
  const int wc = wave & 1;
  const int m15 = lane & 15;
  const int quad = lane >> 4;

  floatx4 acc[4][4];
#pragma unroll
  for (int i = 0; i < 4; ++i)
#pragma unroll
    for (int j = 0; j < 4; ++j) acc[i][j] = (floatx4){0.f, 0.f, 0.f, 0.f};

  const int srow = lane >> 2;
  const int scol = (lane & 3) * 8;

  for (int k0 = 0; k0 < 2048; k0 += 32) {
#pragma unroll
    for (int it = 0; it < 2; ++it) {
      const int rowa = wave * 32 + it * 16;
      const unsigned short* ga = A + (size_t)(bm + rowa + srow) * 2048 + k0 + scol;
      const unsigned short* gb = Bt + (size_t)(bn + rowa + srow) * 2048 + k0 + scol;
      __builtin_amdgcn_global_load_lds(
          (const __attribute__((address_space(1))) void*)ga,
          (__attribute__((address_space(3))) void*)&As[rowa * 32], 16, 0, 0);
      __builtin_amdgcn_global_load_lds(
          (const __attribute__((address_space(1))) void*)gb,
          (__attribute__((address_space(3))) void*)&Bs[rowa * 32], 16, 0, 0);
    }
    __syncthreads();

    short8 af[4], bfr[4];
    const unsigned short* pa = &As[(wr * 64 + m15) * 32 + quad * 8];
    const unsigned short* pb = &Bs[(wc * 64 + m15) * 32 + quad * 8];
#pragma unroll
    for (int i = 0; i < 4; ++i) af[i] = *(const short8*)(pa + i * 16 * 32);
#pragma unroll
    for (int j = 0; j < 4; ++j) bfr[j] = *(const short8*)(pb + j * 16 * 32);
#pragma unroll
    for (int i = 0; i < 4; ++i)
#pragma unroll
      for (int j = 0; j < 4; ++j)
        acc[i][j] = __builtin_amdgcn_mfma_f32_16x16x32_bf16(af[i], bfr[j], acc[i][j], 0, 0, 0);
    __syncthreads();
  }

  // ---- phase 1: acc -> padded bf16 LDS tile (stride 129 halfwords).
#pragma unroll
  for (int i = 0; i < 4; ++i)
#pragma unroll
    for (int j = 0; j < 4; ++j) {
      const int col = wc * 64 + j * 16 + m15;
#pragma unroll
      for (int reg = 0; reg < 4; ++reg) {
        const int row = wr * 64 + i * 16 + quad * 4 + reg;
        smem[row * 129 + col] = f2bf(acc[i][j][reg]);
      }
    }
  __syncthreads();

  // ---- phase 2: per-head epilogue.
  const int t = tid & 63;
  const int wv = tid >> 6;
  const int b = bm >> 11;
  const int l_base = bm & (SEQ - 1);

  if (bx < 20) {
    const float* scale = (bx < NHQ) ? q_scale : k_scale;
    unsigned short* dstbase = (bx < NHQ)
        ? qout + ((size_t)(b * NHQ + bx) * SEQ + l_base) * 128
        : kout + ((size_t)(b * NHK + (bx - NHQ)) * SEQ + l_base) * 128;
    const float sc0 = scale[t];
    const float sc1 = scale[t + 64];
#pragma unroll 4
    for (int rr = 0; rr < 32; ++rr) {
      const int row = wv * 32 + rr;
      const float v0 = bf2f(smem[row * 129 + t]);
      const float v1 = bf2f(smem[row * 129 + t + 64]);
      float ss = v0 * v0 + v1 * v1;
#pragma unroll
      for (int m = 1; m < 64; m <<= 1) ss += __shfl_xor(ss, m);
      const float r = rsqrtf(ss * (1.0f / 128.0f) + 1e-6f);
      const int l = l_base + row;
      const float c0 = cosb[(size_t)l * 128 + t];
      const float s0 = sinb[(size_t)l * 128 + t];
      const float c1 = cosb[(size_t)l * 128 + t + 64];
      const float s1 = sinb[(size_t)l * 128 + t + 64];
      const float a0 = v0 * r * sc0;
      const float a1 = v1 * r * sc1;
      unsigned short* dst = dstbase + (size_t)row * 128;
      dst[t]      = f2bf(a0 * c0 - a1 * s0);
      dst[t + 64] = f2bf(a1 * c1 + a0 * s1);
    }
  } else {
    const int g = bx - 20;
    unsigned short* vbase = vout + (size_t)(b * NHK + g) * 128 * SEQ + l_base;
#pragma unroll 4
    for (int dd = 0; dd < 32; ++dd) {
      const int d = wv * 32 + dd;
      unsigned short* dst = vbase + (size_t)d * SEQ;
      dst[t]      = smem[t * 129 + d];
      dst[t + 64] = smem[(t + 64) * 129 + d];
    }
  }
}

// ---------------------------------------------------------------------------
// bf16 MFMA GEMM (m97 structure): C = A @ B, fp32 out (used for Wo).
// ---------------------------------------------------------------------------
__global__ __launch_bounds__(256) void gemm_bf16_f32(const unsigned short* __restrict__ A,
                                                     const unsigned short* __restrict__ Bt,
                                                     float* __restrict__ C,
                                                     int M, int N, int K) {
  __shared__ unsigned short As[128 * 32];
  __shared__ unsigned short Bs[128 * 32];
  const int tid = threadIdx.x;
  const int wave = tid >> 6;
  const int lane = tid & 63;
  const int bm = blockIdx.y * 128;
  const int bn = blockIdx.x * 128;
  const int wr = wave >> 1;
  const int wc = wave & 1;
  const int m15 = lane & 15;
  const int quad = lane >> 4;

  floatx4 acc[4][4];
#pragma unroll
  for (int i = 0; i < 4; ++i)
#pragma unroll
    for (int j = 0; j < 4; ++j) acc[i][j] = (floatx4){0.f, 0.f, 0.f, 0.f};

  const int srow = lane >> 2;
  const int scol = (lane & 3) * 8;

  for (int k0 = 0; k0 < K; k0 += 32) {
#pragma unroll
    for (int it = 0; it < 2; ++it) {
      const int rowa = wave * 32 + it * 16;
      const unsigned short* ga = A + (size_t)(bm + rowa + srow) * K + k0 + scol;
      const unsigned short* gb = Bt + (size_t)(bn + rowa + srow) * K + k0 + scol;
      __builtin_amdgcn_global_load_lds(
          (const __attribute__((address_space(1))) void*)ga,
          (__attribute__((address_space(3))) void*)&As[rowa * 32], 16, 0, 0);
      __builtin_amdgcn_global_load_lds(
          (const __attribute__((address_space(1))) void*)gb,
          (__attribute__((address_space(3))) void*)&Bs[rowa * 32], 16, 0, 0);
    }
    __syncthreads();

    short8 af[4], bfr[4];
    const unsigned short* pa = &As[(wr * 64 + m15) * 32 + quad * 8];
    const unsigned short* pb = &Bs[(wc * 64 + m15) * 32 + quad * 8];
#pragma unroll
    for (int i = 0; i < 4; ++i) af[i] = *(const short8*)(pa + i * 16 * 32);
#pragma unroll
    for (int j = 0; j < 4; ++j) bfr[j] = *(const short8*)(pb + j * 16 * 32);
#pragma unroll
    for (int i = 0; i < 4; ++i)
#pragma unroll
      for (int j = 0; j < 4; ++j)
        acc[i][j] = __builtin_amdgcn_mfma_f32_16x16x32_bf16(af[i], bfr[j], acc[i][j], 0, 0, 0);
    __syncthreads();
  }

#pragma unroll
  for (int i = 0; i < 4; ++i)
#pragma unroll
    for (int j = 0; j < 4; ++j) {
      const int col = bn + wc * 64 + j * 16 + m15;
#pragma unroll
      for (int reg = 0; reg < 4; ++reg) {
        const int row = bm + wr * 64 + i * 16 + quad * 4 + reg;
        C[(size_t)row * N + col] = acc[i][j][reg];
      }
    }
}

// ---------------------------------------------------------------------------
// MFMA flash attention (causal GQA), no-max softmax.
// |s| = |q.k|/16384 <= 128/16384 by Cauchy-Schwarz (rms-normed q,k, unit
// scales, norm-preserving RoPE) -> exp(s) can't overflow; no running max.
// R8: Ps aliased over Ks (Ks dead after QK, Ps born after) at the cost of one
// extra barrier per tile. LDS 42 -> 32 KB => 5 blocks/CU, all 1024 blocks
// co-resident (20 waves/CU) to absorb the barrier drains.
// NOTE (R5 lesson): BM=128 spills accumulators to scratch. Keep 8 acc/wave.
// ---------------------------------------------------------------------------
__global__ __launch_bounds__(256, 5) void attn_mfma(const unsigned short* __restrict__ qb,
                                                    const unsigned short* __restrict__ kb,
                                                    const unsigned short* __restrict__ vtb,
                                                    unsigned short* __restrict__ o) {
  __shared__ unsigned short Ks[64 * 128];   // QK phase: K tile; PV phase: Ps (stride 72)
  __shared__ unsigned short Vs[128 * 64];
  unsigned short* Ps = Ks;

  const int tid = threadIdx.x;
  const int wave = tid >> 6;
  const int lane = tid & 63;
  const int m15 = lane & 15;
  const int quad = lane >> 4;
  const int bh = blockIdx.x;           // 0..31
  const int b = bh >> 4;
  const int h = bh & 15;
  const int g = h >> 2;
  const int q0 = ((int)gridDim.y - 1 - (int)blockIdx.y) * 64;  // longest first

  const unsigned short* qhead = qb + (size_t)bh * SEQ * 128;
  const unsigned short* khead = kb + (size_t)(b * NHK + g) * SEQ * 128;
  const unsigned short* vthead = vtb + (size_t)(b * NHK + g) * 128 * SEQ;

  short8 qf[4];
  {
    const unsigned short* qp = qhead + (size_t)(q0 + wave * 16 + m15) * 128 + quad * 8;
#pragma unroll
    for (int ks = 0; ks < 4; ++ks) qf[ks] = *(const short8*)(qp + ks * 32);
  }

  floatx4 acc_o[8];
#pragma unroll
  for (int n = 0; n < 8; ++n) acc_o[n] = (floatx4){0.f, 0.f, 0.f, 0.f};
  float l_lane[4] = {0.f, 0.f, 0.f, 0.f};
  const float inv_scale = 1.0f / 16384.0f;

  for (int j0 = 0; j0 <= q0; j0 += 64) {
    // ---- stage K tile (64 x 128, chunk-XOR swizzle) and Vt tile (128 x 64)
#pragma unroll
    for (int t = 0; t < 4; ++t) {
      const int r = wave * 16 + t * 4 + (lane >> 4);
      const int cg = (lane & 15) ^ (r & 15);
      const unsigned short* src = khead + (size_t)(j0 + r) * 128 + cg * 8;
      __builtin_amdgcn_global_load_lds(
          (const __attribute__((address_space(1))) void*)src,
          (__attribute__((address_space(3))) void*)&Ks[(wave * 16 + t * 4) * 128], 16, 0, 0);
    }
#pragma unroll
    for (int t = 0; t < 4; ++t) {
      const int d = wave * 32 + t * 8 + (lane >> 3);
      const int cg = (lane & 7) ^ (d & 7);
      const unsigned short* src = vthead + (size_t)d * SEQ + j0 + cg * 8;
      __builtin_amdgcn_global_load_lds(
          (const __attribute__((address_space(1))) void*)src,
          (__attribute__((address_space(3))) void*)&Vs[(wave * 32 + t * 8) * 64], 16, 0, 0);
    }
    __syncthreads();

    // ---- S = Q K^T
    floatx4 acc_s[4];
#pragma unroll
    for (int n = 0; n < 4; ++n) acc_s[n] = (floatx4){0.f, 0.f, 0.f, 0.f};
#pragma unroll
    for (int ks = 0; ks < 4; ++ks) {
#pragma unroll
      for (int n = 0; n < 4; ++n) {
        const short8 bfrag = *(const short8*)&Ks[(n * 16 + m15) * 128 + (((ks * 4 + quad) ^ m15) * 8)];
        acc_s[n] = __builtin_amdgcn_mfma_f32_16x16x32_bf16(qf[ks], bfrag, acc_s[n], 0, 0, 0);
      }
    }
    __syncthreads();   // all waves done reading Ks before Ps overwrites it

    // ---- p = exp(s/16384) -> Ps (over Ks region); mask only diagonal tile.
    if (j0 == q0) {
      const int row_g = wave * 16 + quad * 4;
#pragma unroll
      for (int n = 0; n < 4; ++n) {
        const int col = n * 16 + m15;
#pragma unroll
        for (int rg = 0; rg < 4; ++rg) {
          float p = (col > row_g + rg) ? 0.0f : __expf(acc_s[n][rg] * inv_scale);
          l_lane[rg] += p;
          Ps[(wave * 16 + quad * 4 + rg) * 72 + n * 16 + m15] = f2bf(p);
        }
      }
    } else {
#pragma unroll
      for (int n = 0; n < 4; ++n) {
#pragma unroll
        for (int rg = 0; rg < 4; ++rg) {
          const float p = __expf(acc_s[n][rg] * inv_scale);
          l_lane[rg] += p;
          Ps[(wave * 16 + quad * 4 + rg) * 72 + n * 16 + m15] = f2bf(p);
        }
      }
    }

    // ---- O += P V  (Ps rows wave-private: same-wave write->read, in-order)
#pragma unroll
    for (int kk = 0; kk < 2; ++kk) {
      const short8 a = *(const short8*)&Ps[(wave * 16 + m15) * 72 + kk * 32 + quad * 8];
#pragma unroll
      for (int n = 0; n < 8; ++n) {
        const short8 bfrag = *(const short8*)&Vs[(n * 16 + m15) * 64 + (((kk * 4 + quad) ^ (m15 & 7)) * 8)];
        acc_o[n] = __builtin_amdgcn_mfma_f32_16x16x32_bf16(a, bfrag, acc_o[n], 0, 0, 0);
      }
    }
    __syncthreads();   // Ps reads done before next iteration restages Ks
  }

#pragma unroll
  for (int rg = 0; rg < 4; ++rg) {
    float l = l_lane[rg];
    l += __shfl_xor(l, 1);
    l += __shfl_xor(l, 2);
    l += __shfl_xor(l, 4);
    l += __shfl_xor(l, 8);
    const float invl = 1.0f / l;
    const size_t row = (size_t)(b * SEQ + q0 + wave * 16 + quad * 4 + rg);
#pragma unroll
    for (int n = 0; n < 8; ++n)
      o[row * DMODEL + h * 128 + n * 16 + m15] = f2bf(acc_o[n][rg] * invl);
  }
}

// ---------------------------------------------------------------------------
extern "C" void kernel_launch(void* const* d_in, const int* in_sizes, int n_in,
                              void* d_out, int out_size, void* d_ws, size_t ws_size,
                              hipStream_t stream) {
  const float* x       = (const float*)d_in[0];
  const float* Wq      = (const float*)d_in[1];
  const float* Wk      = (const float*)d_in[2];
  const float* Wv      = (const float*)d_in[3];
  const float* Wo      = (const float*)d_in[4];
  const float* q_scale = (const float*)d_in[5];
  const float* k_scale = (const float*)d_in[6];
  const float* cosb    = (const float*)d_in[7];
  const float* sinb    = (const float*)d_in[8];
  float* out = (float*)d_out;

  // Workspace (79.69 MB, no overlays; 83.9 MB proven available):
  char* w = (char*)d_ws;
  unsigned short* x_bf    = (unsigned short*)w;               // [0, 16.78M)
  unsigned short* wqkv_t  = (unsigned short*)(w + 16777216);  // [16.78M, 29.36M)
  unsigned short* q_bf    = (unsigned short*)(w + 29360128);  // [29.36M, 46.14M)
  unsigned short* k_bf    = (unsigned short*)(w + 46137344);  // [46.14M, 50.33M)
  unsigned short* vt      = (unsigned short*)(w + 50331648);  // [50.33M, 54.53M)
  unsigned short* wo_t    = (unsigned short*)(w + 54525952);  // [54.53M, 62.91M)
  unsigned short* attn_bf = (unsigned short*)(w + 62914560);  // [62.91M, 79.69M)

  // One prep launch: cast x + all weight transposes.
  prep<<<dim3(64, 64, 4), dim3(32, 8), 0, stream>>>(x, Wq, Wk, Wv, Wo, x_bf, wqkv_t, wo_t);

  // Fused QKV projection + RMSNorm + RoPE + V-transpose.
  gemm_qkv_fused<<<dim3(24, 32), 256, 0, stream>>>(x_bf, wqkv_t, q_bf, k_bf, vt,
                                                   q_scale, k_scale, cosb, sinb);

  // Attention, then output projection.
  attn_mfma<<<dim3(2 * NHQ, SEQ / 64), 256, 0, stream>>>(q_bf, k_bf, vt, attn_bf);
  gemm_bf16_f32<<<dim3(2048 / 128, 4096 / 128), 256, 0, stream>>>(
      attn_bf, wo_t, out, 4096, 2048, 2048);
}

// Round 9
// 318.814 us; speedup vs baseline: 1.2332x; 1.2332x over previous
//
#include <hip/hip_runtime.h>
#include <math.h>

// Problem constants (fixed by reference):
// B=2, L=2048, D=2048, H=16, G=4, HD=128, EPS=1e-6, scale = 1/HD^2 = 1/16384
#define SEQ 2048
#define DMODEL 2048
#define NHQ 16
#define NHK 4

typedef __attribute__((ext_vector_type(8))) short short8;
typedef __attribute__((ext_vector_type(4))) float floatx4;

__device__ __forceinline__ unsigned short f2bf(float f) {
  unsigned int u = __builtin_bit_cast(unsigned int, f);
  u += 0x7fffu + ((u >> 16) & 1u);   // round-to-nearest-even
  return (unsigned short)(u >> 16);
}
__device__ __forceinline__ float bf2f(unsigned short s) {
  unsigned int u = ((unsigned int)s) << 16;
  return __builtin_bit_cast(float, u);
}

// ---------------------------------------------------------------------------
// One prep launch: cast x -> bf16 AND all 4 weight transposes.
// grid (64, 64, 4), block (32,8).
//  z=0: Wq -> wqkv_t[0:2048]           z=1: Wo -> wo_t
//  z=2: bx<16 Wk -> wqkv_t[2048:2560]; bx in [16,32) Wv -> wqkv_t[2560:3072]
//  z=3: cast x (block = 2048 contiguous elements)
// ---------------------------------------------------------------------------
__global__ __launch_bounds__(256) void prep(const float* __restrict__ x,
                                            const float* __restrict__ Wq,
                                            const float* __restrict__ Wk,
                                            const float* __restrict__ Wv,
                                            const float* __restrict__ Wo,
                                            unsigned short* __restrict__ x_bf,
                                            unsigned short* __restrict__ wqkv_t,
                                            unsigned short* __restrict__ wo_t) {
  const int z = blockIdx.z;
  const int tx = threadIdx.x, ty = threadIdx.y;
  if (z == 3) {
    const size_t base = ((size_t)(blockIdx.y * 64 + blockIdx.x)) * 2048 + (ty * 32 + tx) * 8;
    const float4 v0 = *(const float4*)(x + base);
    const float4 v1 = *(const float4*)(x + base + 4);
    ushort4 w0, w1;
    w0.x = f2bf(v0.x); w0.y = f2bf(v0.y); w0.z = f2bf(v0.z); w0.w = f2bf(v0.w);
    w1.x = f2bf(v1.x); w1.y = f2bf(v1.y); w1.z = f2bf(v1.z); w1.w = f2bf(v1.w);
    *(ushort4*)(x_bf + base) = w0;
    *(ushort4*)(x_bf + base + 4) = w1;
    return;
  }
  int bx = blockIdx.x;
  const float* in;
  unsigned short* out;
  int C;
  const int R = 2048;
  if (z == 0)      { in = Wq; out = wqkv_t;                          C = 2048; }
  else if (z == 1) { in = Wo; out = wo_t;                            C = 2048; }
  else {
    if (bx < 16)      { in = Wk; out = wqkv_t + (size_t)2048 * 2048; C = 512; }
    else if (bx < 32) { in = Wv; out = wqkv_t + (size_t)2560 * 2048; C = 512; bx -= 16; }
    else return;
  }
  __shared__ float tile[32][33];
  const int c0 = bx * 32, r0 = blockIdx.y * 32;
#pragma unroll
  for (int j = 0; j < 4; ++j)
    tile[ty + j * 8][tx] = in[(size_t)(r0 + ty + j * 8) * C + c0 + tx];
  __syncthreads();
#pragma unroll
  for (int j = 0; j < 4; ++j)
    out[(size_t)(c0 + ty + j * 8) * R + r0 + tx] = f2bf(tile[tx][ty + j * 8]);
}

// ---------------------------------------------------------------------------
// Fused QKV GEMM + RMSNorm + RoPE + V-transpose (unchanged from R7).
// Each 128-col block tile is exactly one head: bx<16 Q, 16..19 K, 20..23 V.
// ---------------------------------------------------------------------------
__global__ __launch_bounds__(256) void gemm_qkv_fused(const unsigned short* __restrict__ A,
                                                      const unsigned short* __restrict__ Bt,
                                                      unsigned short* __restrict__ qout,
                                                      unsigned short* __restrict__ kout,
                                                      unsigned short* __restrict__ vout,
                                                      const float* __restrict__ q_scale,
                                                      const float* __restrict__ k_scale,
                                                      const float* __restrict__ cosb,
                                                      const float* __restrict__ sinb) {
  __shared__ unsigned short smem[128 * 129];   // 33 KB; first 16 KB doubles as As|Bs
  unsigned short* As = smem;
  unsigned short* Bs = smem + 128 * 32;

  const int tid = threadIdx.x;
  const int wave = tid >> 6;
  const int lane = tid & 63;
  const int bm = blockIdx.y * 128;
  const int bx = blockIdx.x;            // head-block 0..23
  const int bn = bx * 128;
  const int wr = wave >> 1;
  const int wc = wave & 1;
  const int m15 = lane & 15;
  const int quad = lane >> 4;

  floatx4 acc[4][4];
#pragma unroll
  for (int i = 0; i < 4; ++i)
#pragma unroll
    for (int j = 0; j < 4; ++j) acc[i][j] = (floatx4){0.f, 0.f, 0.f, 0.f};

  const int srow = lane >> 2;
  const int scol = (lane & 3) * 8;

  for (int k0 = 0; k0 < 2048; k0 += 32) {
#pragma unroll
    for (int it = 0; it < 2; ++it) {
      const int rowa = wave * 32 + it * 16;
      const unsigned short* ga = A + (size_t)(bm + rowa + srow) * 2048 + k0 + scol;
      const unsigned short* gb = Bt + (size_t)(bn + rowa + srow) * 2048 + k0 + scol;
      __builtin_amdgcn_global_load_lds(
          (const __attribute__((address_space(1))) void*)ga,
          (__attribute__((address_space(3))) void*)&As[rowa * 32], 16, 0, 0);
      __builtin_amdgcn_global_load_lds(
          (const __attribute__((address_space(1))) void*)gb,
          (__attribute__((address_space(3))) void*)&Bs[rowa * 32], 16, 0, 0);
    }
    __syncthreads();

    short8 af[4], bfr[4];
    const unsigned short* pa = &As[(wr * 64 + m15) * 32 + quad * 8];
    const unsigned short* pb = &Bs[(wc * 64 + m15) * 32 + quad * 8];
#pragma unroll
    for (int i = 0; i < 4; ++i) af[i] = *(const short8*)(pa + i * 16 * 32);
#pragma unroll
    for (int j = 0; j < 4; ++j) bfr[j] = *(const short8*)(pb + j * 16 * 32);
#pragma unroll
    for (int i = 0; i < 4; ++i)
#pragma unroll
      for (int j = 0; j < 4; ++j)
        acc[i][j] = __builtin_amdgcn_mfma_f32_16x16x32_bf16(af[i], bfr[j], acc[i][j], 0, 0, 0);
    __syncthreads();
  }

  // ---- phase 1: acc -> padded bf16 LDS tile (stride 129 halfwords).
#pragma unroll
  for (int i = 0; i < 4; ++i)
#pragma unroll
    for (int j = 0; j < 4; ++j) {
      const int col = wc * 64 + j * 16 + m15;
#pragma unroll
      for (int reg = 0; reg < 4; ++reg) {
        const int row = wr * 64 + i * 16 + quad * 4 + reg;
        smem[row * 129 + col] = f2bf(acc[i][j][reg]);
      }
    }
  __syncthreads();

  // ---- phase 2: per-head epilogue.
  const int t = tid & 63;
  const int wv = tid >> 6;
  const int b = bm >> 11;
  const int l_base = bm & (SEQ - 1);

  if (bx < 20) {
    const float* scale = (bx < NHQ) ? q_scale : k_scale;
    unsigned short* dstbase = (bx < NHQ)
        ? qout + ((size_t)(b * NHQ + bx) * SEQ + l_base) * 128
        : kout + ((size_t)(b * NHK + (bx - NHQ)) * SEQ + l_base) * 128;
    const float sc0 = scale[t];
    const float sc1 = scale[t + 64];
#pragma unroll 4
    for (int rr = 0; rr < 32; ++rr) {
      const int row = wv * 32 + rr;
      const float v0 = bf2f(smem[row * 129 + t]);
      const float v1 = bf2f(smem[row * 129 + t + 64]);
      float ss = v0 * v0 + v1 * v1;
#pragma unroll
      for (int m = 1; m < 64; m <<= 1) ss += __shfl_xor(ss, m);
      const float r = rsqrtf(ss * (1.0f / 128.0f) + 1e-6f);
      const int l = l_base + row;
      const float c0 = cosb[(size_t)l * 128 + t];
      const float s0 = sinb[(size_t)l * 128 + t];
      const float c1 = cosb[(size_t)l * 128 + t + 64];
      const float s1 = sinb[(size_t)l * 128 + t + 64];
      const float a0 = v0 * r * sc0;
      const float a1 = v1 * r * sc1;
      unsigned short* dst = dstbase + (size_t)row * 128;
      dst[t]      = f2bf(a0 * c0 - a1 * s0);
      dst[t + 64] = f2bf(a1 * c1 + a0 * s1);
    }
  } else {
    const int g = bx - 20;
    unsigned short* vbase = vout + (size_t)(b * NHK + g) * 128 * SEQ + l_base;
#pragma unroll 4
    for (int dd = 0; dd < 32; ++dd) {
      const int d = wv * 32 + dd;
      unsigned short* dst = vbase + (size_t)d * SEQ;
      dst[t]      = smem[t * 129 + d];
      dst[t + 64] = smem[(t + 64) * 129 + d];
    }
  }
}

// ---------------------------------------------------------------------------
// bf16 MFMA GEMM (m97 structure): C = A @ B, fp32 out (used for Wo).
// ---------------------------------------------------------------------------
__global__ __launch_bounds__(256) void gemm_bf16_f32(const unsigned short* __restrict__ A,
                                                     const unsigned short* __restrict__ Bt,
                                                     float* __restrict__ C,
                                                     int M, int N, int K) {
  __shared__ unsigned short As[128 * 32];
  __shared__ unsigned short Bs[128 * 32];
  const int tid = threadIdx.x;
  const int wave = tid >> 6;
  const int lane = tid & 63;
  const int bm = blockIdx.y * 128;
  const int bn = blockIdx.x * 128;
  const int wr = wave >> 1;
  const int wc = wave & 1;
  const int m15 = lane & 15;
  const int quad = lane >> 4;

  floatx4 acc[4][4];
#pragma unroll
  for (int i = 0; i < 4; ++i)
#pragma unroll
    for (int j = 0; j < 4; ++j) acc[i][j] = (floatx4){0.f, 0.f, 0.f, 0.f};

  const int srow = lane >> 2;
  const int scol = (lane & 3) * 8;

  for (int k0 = 0; k0 < K; k0 += 32) {
#pragma unroll
    for (int it = 0; it < 2; ++it) {
      const int rowa = wave * 32 + it * 16;
      const unsigned short* ga = A + (size_t)(bm + rowa + srow) * K + k0 + scol;
      const unsigned short* gb = Bt + (size_t)(bn + rowa + srow) * K + k0 + scol;
      __builtin_amdgcn_global_load_lds(
          (const __attribute__((address_space(1))) void*)ga,
          (__attribute__((address_space(3))) void*)&As[rowa * 32], 16, 0, 0);
      __builtin_amdgcn_global_load_lds(
          (const __attribute__((address_space(1))) void*)gb,
          (__attribute__((address_space(3))) void*)&Bs[rowa * 32], 16, 0, 0);
    }
    __syncthreads();

    short8 af[4], bfr[4];
    const unsigned short* pa = &As[(wr * 64 + m15) * 32 + quad * 8];
    const unsigned short* pb = &Bs[(wc * 64 + m15) * 32 + quad * 8];
#pragma unroll
    for (int i = 0; i < 4; ++i) af[i] = *(const short8*)(pa + i * 16 * 32);
#pragma unroll
    for (int j = 0; j < 4; ++j) bfr[j] = *(const short8*)(pb + j * 16 * 32);
#pragma unroll
    for (int i = 0; i < 4; ++i)
#pragma unroll
      for (int j = 0; j < 4; ++j)
        acc[i][j] = __builtin_amdgcn_mfma_f32_16x16x32_bf16(af[i], bfr[j], acc[i][j], 0, 0, 0);
    __syncthreads();
  }

#pragma unroll
  for (int i = 0; i < 4; ++i)
#pragma unroll
    for (int j = 0; j < 4; ++j) {
      const int col = bn + wc * 64 + j * 16 + m15;
#pragma unroll
      for (int reg = 0; reg < 4; ++reg) {
        const int row = bm + wr * 64 + i * 16 + quad * 4 + reg;
        C[(size_t)row * N + col] = acc[i][j][reg];
      }
    }
}

// ---------------------------------------------------------------------------
// MFMA flash attention (causal GQA), no-max softmax.
// |s| = |q.k|/16384 <= 128/16384 by Cauchy-Schwarz (rms-normed q,k, unit
// scales, norm-preserving RoPE) -> exp(s) can't overflow; no running max.
// Ps aliased over Ks (Ks dead after QK, Ps born after): LDS 42 -> 32 KB.
// __launch_bounds__(256, 4): VGPR cap 128 >= the ~68 this kernel needs ->
// 4 blocks/CU with NO spill.
// R8 lesson: (256,5) capped VGPR at ~102, allocator went to 48 and spilled
// acc_o to scratch (WRITE_SIZE 16->114 MB, 2.2x slower). R5 lesson: BM=128
// spills likewise. The live set (8 acc_o + 4 qf + 4 acc_s x4) needs ~128 cap.
// ---------------------------------------------------------------------------
__global__ __launch_bounds__(256, 4) void attn_mfma(const unsigned short* __restrict__ qb,
                                                    const unsigned short* __restrict__ kb,
                                                    const unsigned short* __restrict__ vtb,
                                                    unsigned short* __restrict__ o) {
  __shared__ unsigned short Ks[64 * 128];   // QK phase: K tile; PV phase: Ps (stride 72)
  __shared__ unsigned short Vs[128 * 64];
  unsigned short* Ps = Ks;

  const int tid = threadIdx.x;
  const int wave = tid >> 6;
  const int lane = tid & 63;
  const int m15 = lane & 15;
  const int quad = lane >> 4;
  const int bh = blockIdx.x;           // 0..31
  const int b = bh >> 4;
  const int h = bh & 15;
  const int g = h >> 2;
  const int q0 = ((int)gridDim.y - 1 - (int)blockIdx.y) * 64;  // longest first

  const unsigned short* qhead = qb + (size_t)bh * SEQ * 128;
  const unsigned short* khead = kb + (size_t)(b * NHK + g) * SEQ * 128;
  const unsigned short* vthead = vtb + (size_t)(b * NHK + g) * 128 * SEQ;

  short8 qf[4];
  {
    const unsigned short* qp = qhead + (size_t)(q0 + wave * 16 + m15) * 128 + quad * 8;
#pragma unroll
    for (int ks = 0; ks < 4; ++ks) qf[ks] = *(const short8*)(qp + ks * 32);
  }

  floatx4 acc_o[8];
#pragma unroll
  for (int n = 0; n < 8; ++n) acc_o[n] = (floatx4){0.f, 0.f, 0.f, 0.f};
  float l_lane[4] = {0.f, 0.f, 0.f, 0.f};
  const float inv_scale = 1.0f / 16384.0f;

  for (int j0 = 0; j0 <= q0; j0 += 64) {
    // ---- stage K tile (64 x 128, chunk-XOR swizzle) and Vt tile (128 x 64)
#pragma unroll
    for (int t = 0; t < 4; ++t) {
      const int r = wave * 16 + t * 4 + (lane >> 4);
      const int cg = (lane & 15) ^ (r & 15);
      const unsigned short* src = khead + (size_t)(j0 + r) * 128 + cg * 8;
      __builtin_amdgcn_global_load_lds(
          (const __attribute__((address_space(1))) void*)src,
          (__attribute__((address_space(3))) void*)&Ks[(wave * 16 + t * 4) * 128], 16, 0, 0);
    }
#pragma unroll
    for (int t = 0; t < 4; ++t) {
      const int d = wave * 32 + t * 8 + (lane >> 3);
      const int cg = (lane & 7) ^ (d & 7);
      const unsigned short* src = vthead + (size_t)d * SEQ + j0 + cg * 8;
      __builtin_amdgcn_global_load_lds(
          (const __attribute__((address_space(1))) void*)src,
          (__attribute__((address_space(3))) void*)&Vs[(wave * 32 + t * 8) * 64], 16, 0, 0);
    }
    __syncthreads();

    // ---- S = Q K^T
    floatx4 acc_s[4];
#pragma unroll
    for (int n = 0; n < 4; ++n) acc_s[n] = (floatx4){0.f, 0.f, 0.f, 0.f};
#pragma unroll
    for (int ks = 0; ks < 4; ++ks) {
#pragma unroll
      for (int n = 0; n < 4; ++n) {
        const short8 bfrag = *(const short8*)&Ks[(n * 16 + m15) * 128 + (((ks * 4 + quad) ^ m15) * 8)];
        acc_s[n] = __builtin_amdgcn_mfma_f32_16x16x32_bf16(qf[ks], bfrag, acc_s[n], 0, 0, 0);
      }
    }
    __syncthreads();   // all waves done reading Ks before Ps overwrites it

    // ---- p = exp(s/16384) -> Ps (over Ks region); mask only diagonal tile.
    if (j0 == q0) {
      const int row_g = wave * 16 + quad * 4;
#pragma unroll
      for (int n = 0; n < 4; ++n) {
        const int col = n * 16 + m15;
#pragma unroll
        for (int rg = 0; rg < 4; ++rg) {
          float p = (col > row_g + rg) ? 0.0f : __expf(acc_s[n][rg] * inv_scale);
          l_lane[rg] += p;
          Ps[(wave * 16 + quad * 4 + rg) * 72 + n * 16 + m15] = f2bf(p);
        }
      }
    } else {
#pragma unroll
      for (int n = 0; n < 4; ++n) {
#pragma unroll
        for (int rg = 0; rg < 4; ++rg) {
          const float p = __expf(acc_s[n][rg] * inv_scale);
          l_lane[rg] += p;
          Ps[(wave * 16 + quad * 4 + rg) * 72 + n * 16 + m15] = f2bf(p);
        }
      }
    }

    // ---- O += P V  (Ps rows wave-private: same-wave write->read, in-order)
#pragma unroll
    for (int kk = 0; kk < 2; ++kk) {
      const short8 a = *(const short8*)&Ps[(wave * 16 + m15) * 72 + kk * 32 + quad * 8];
#pragma unroll
      for (int n = 0; n < 8; ++n) {
        const short8 bfrag = *(const short8*)&Vs[(n * 16 + m15) * 64 + (((kk * 4 + quad) ^ (m15 & 7)) * 8)];
        acc_o[n] = __builtin_amdgcn_mfma_f32_16x16x32_bf16(a, bfrag, acc_o[n], 0, 0, 0);
      }
    }
    __syncthreads();   // Ps reads done before next iteration restages Ks
  }

#pragma unroll
  for (int rg = 0; rg < 4; ++rg) {
    float l = l_lane[rg];
    l += __shfl_xor(l, 1);
    l += __shfl_xor(l, 2);
    l += __shfl_xor(l, 4);
    l += __shfl_xor(l, 8);
    const float invl = 1.0f / l;
    const size_t row = (size_t)(b * SEQ + q0 + wave * 16 + quad * 4 + rg);
#pragma unroll
    for (int n = 0; n < 8; ++n)
      o[row * DMODEL + h * 128 + n * 16 + m15] = f2bf(acc_o[n][rg] * invl);
  }
}

// ---------------------------------------------------------------------------
extern "C" void kernel_launch(void* const* d_in, const int* in_sizes, int n_in,
                              void* d_out, int out_size, void* d_ws, size_t ws_size,
                              hipStream_t stream) {
  const float* x       = (const float*)d_in[0];
  const float* Wq      = (const float*)d_in[1];
  const float* Wk      = (const float*)d_in[2];
  const float* Wv      = (const float*)d_in[3];
  const float* Wo      = (const float*)d_in[4];
  const float* q_scale = (const float*)d_in[5];
  const float* k_scale = (const float*)d_in[6];
  const float* cosb    = (const float*)d_in[7];
  const float* sinb    = (const float*)d_in[8];
  float* out = (float*)d_out;

  // Workspace (79.69 MB, no overlays; 83.9 MB proven available):
  char* w = (char*)d_ws;
  unsigned short* x_bf    = (unsigned short*)w;               // [0, 16.78M)
  unsigned short* wqkv_t  = (unsigned short*)(w + 16777216);  // [16.78M, 29.36M)
  unsigned short* q_bf    = (unsigned short*)(w + 29360128);  // [29.36M, 46.14M)
  unsigned short* k_bf    = (unsigned short*)(w + 46137344);  // [46.14M, 50.33M)
  unsigned short* vt      = (unsigned short*)(w + 50331648);  // [50.33M, 54.53M)
  unsigned short* wo_t    = (unsigned short*)(w + 54525952);  // [54.53M, 62.91M)
  unsigned short* attn_bf = (unsigned short*)(w + 62914560);  // [62.91M, 79.69M)

  // One prep launch: cast x + all weight transposes.
  prep<<<dim3(64, 64, 4), dim3(32, 8), 0, stream>>>(x, Wq, Wk, Wv, Wo, x_bf, wqkv_t, wo_t);

  // Fused QKV projection + RMSNorm + RoPE + V-transpose.
  gemm_qkv_fused<<<dim3(24, 32), 256, 0, stream>>>(x_bf, wqkv_t, q_bf, k_bf, vt,
                                                   q_scale, k_scale, cosb, sinb);

  // Attention, then output projection.
  attn_mfma<<<dim3(2 * NHQ, SEQ / 64), 256, 0, stream>>>(q_bf, k_bf, vt, attn_bf);
  gemm_bf16_f32<<<dim3(2048 / 128, 4096 / 128), 256, 0, stream>>>(
      attn_bf, wo_t, out, 4096, 2048, 2048);
}